// Round 6
// baseline (1335.966 us; speedup 1.0000x reference)
//
#include <hip/hip_runtime.h>
#include <math.h>

#define HH 2048
#define WW 2048
#define NIMG 4
#define NCH 3
#define PLANES (NIMG*NCH)            // 12
#define PIX (HH*WW)                  // 4194304
#define TOT (PLANES*PIX)             // 50331648
#define W4 (WW/4)                    // 512
#define MED_RANK 25165823u           // floor(0.5*(TOT-1)), method='lower'

struct GW { float w[7]; };

// ---------------- module-global device state ----------------
__device__ unsigned g_hist1[4096];
__device__ unsigned g_hist2[4096];
__device__ unsigned g_hist3[256];
__device__ unsigned g_ctrl[8];   // [0]=b1 [1]=b2 [2]=b3 [3]=rank2 [4]=rank3
__device__ float    g_med;

// All cross-kernel state is written with atomicExch and read with atomicAdd(p,0)
// (once per block, staged via LDS) so every access hits the coherent point —
// no reliance on per-XCD L2 writeback/invalidate for plain loads/stores.
__global__ void zero_state() {
    int t = blockIdx.x * 256 + threadIdx.x;
    if (t < 4096) { atomicExch(&g_hist1[t], 0u); atomicExch(&g_hist2[t], 0u); }
    if (t < 256)  atomicExch(&g_hist3[t], 0u);
    if (t < 8)    atomicExch(&g_ctrl[t], 0u);
    if (t == 0)   atomicExch(&g_med, 0.f);
}

// ---------------- Pass A: fused Sobel + horizontal Gaussian ----------------
__global__ __launch_bounds__(256) void sobel_gauss_h(const float* __restrict__ x,
                                                     float* __restrict__ Bh, GW g) {
    int w0 = (blockIdx.x * 256 + threadIdx.x) * 4;     // 0..2044
    int h  = blockIdx.y;
    int n  = blockIdx.z;
    const float* xp = x + (size_t)n * PIX;
    const float* p0 = xp + (size_t)(h - 1) * WW;
    const float* p1 = xp + (size_t)h * WW;
    const float* p2 = xp + (size_t)(h + 1) * WW;
    bool has0 = (h > 0), has2 = (h < HH - 1);

    float r0[12], r1[12], r2[12];
    if (w0 >= 4 && w0 <= WW - 8) {          // interior: 9 float4 loads
#pragma unroll
        for (int b = 0; b < 3; b++) {
            int col = w0 - 4 + b * 4;
            float4 v0 = has0 ? *(const float4*)(p0 + col) : make_float4(0, 0, 0, 0);
            float4 v1 = *(const float4*)(p1 + col);
            float4 v2 = has2 ? *(const float4*)(p2 + col) : make_float4(0, 0, 0, 0);
            r0[b*4+0]=v0.x; r0[b*4+1]=v0.y; r0[b*4+2]=v0.z; r0[b*4+3]=v0.w;
            r1[b*4+0]=v1.x; r1[b*4+1]=v1.y; r1[b*4+2]=v1.z; r1[b*4+3]=v1.w;
            r2[b*4+0]=v2.x; r2[b*4+1]=v2.y; r2[b*4+2]=v2.z; r2[b*4+3]=v2.w;
        }
    } else {
#pragma unroll
        for (int i = 0; i < 12; i++) {
            int col = w0 - 4 + i;
            bool okc = (col >= 0 && col < WW);
            r0[i] = (okc && has0) ? p0[col] : 0.f;
            r1[i] =  okc          ? p1[col] : 0.f;
            r2[i] = (okc && has2) ? p2[col] : 0.f;
        }
    }

    float pxx[10], pyy[10], pxy[10];
#pragma unroll
    for (int c = 0; c < 10; c++) {
        int ai = c + 1;
        int cg = w0 - 3 + c;
        float Ix = (r0[ai+1] - r0[ai-1]) + 2.f*(r1[ai+1] - r1[ai-1]) + (r2[ai+1] - r2[ai-1]);
        float Iy = (r2[ai-1] - r0[ai-1]) + 2.f*(r2[ai]   - r0[ai])   + (r2[ai+1] - r0[ai+1]);
        bool ok = (cg >= 0 && cg < WW);
        pxx[c] = ok ? Ix * Ix : 0.f;
        pyy[c] = ok ? Iy * Iy : 0.f;
        pxy[c] = ok ? Ix * Iy : 0.f;
    }

    float oxx[4], oyy[4], oxy[4];
#pragma unroll
    for (int k = 0; k < 4; k++) {
        float sxx = 0.f, syy = 0.f, sxy = 0.f;
#pragma unroll
        for (int j = 0; j < 7; j++) {
            sxx += g.w[j] * pxx[k + j];
            syy += g.w[j] * pyy[k + j];
            sxy += g.w[j] * pxy[k + j];
        }
        oxx[k] = sxx; oyy[k] = syy; oxy[k] = sxy;
    }

    size_t base = (size_t)(n * NCH) * PIX + (size_t)h * WW + w0;
    *(float4*)(Bh + base)           = make_float4(oxx[0], oxx[1], oxx[2], oxx[3]);
    *(float4*)(Bh + base + PIX)     = make_float4(oyy[0], oyy[1], oyy[2], oyy[3]);
    *(float4*)(Bh + base + 2*PIX)   = make_float4(oxy[0], oxy[1], oxy[2], oxy[3]);
}

// ---------------- Median helpers ----------------
__device__ __forceinline__ unsigned f2key(float f) {
    unsigned b = __float_as_uint(f);
    return (b & 0x80000000u) ? ~b : (b | 0x80000000u);
}

__device__ __forceinline__ void hist4(unsigned* myh, const float4& a) {
    unsigned b0 = f2key(a.x) >> 20, b1 = f2key(a.y) >> 20,
             b2 = f2key(a.z) >> 20, b3 = f2key(a.w) >> 20;
    if (b0 == b1 && b0 == b2 && b0 == b3) {      // spatially-correlated fast path
        atomicAdd(&myh[b0], 4u);
    } else {
        atomicAdd(&myh[b0], 1u); atomicAdd(&myh[b1], 1u);
        atomicAdd(&myh[b2], 1u); atomicAdd(&myh[b3], 1u);
    }
}

// ---------------- Pass B: vertical Gaussian + fused hist0 ----------------
// Thread = one float4 column x 4 consecutive output rows: 10 guarded loads ->
// 4 outputs (2.5x read amplification vs 7x for 1-row threads). Non-strided
// exact launch: 12 planes * 512 row-groups * 512 cols / 256 = 12288 blocks.
__global__ __launch_bounds__(256) void gauss_v_hist(const float* __restrict__ Bh,
                                                    float* __restrict__ S, GW g) {
    __shared__ unsigned lh[2 * 4096];            // 2 lane-parity copies, 32 KB
    for (int i = threadIdx.x; i < 2 * 4096; i += 256) lh[i] = 0;
    __syncthreads();
    unsigned* myh = lh + (threadIdx.x & 1) * 4096;

    int e = blockIdx.x * 256 + threadIdx.x;      // < 12*512*512 = 3145728
    int col4  = e & (W4 - 1);
    int rg    = (e >> 9) & 511;
    int plane = e >> 18;                         // < 12
    int rbase = rg * 4;
    const float4* bp = (const float4*)Bh + (size_t)plane * (PIX / 4) + col4;
    float4*       sp = (float4*)S        + (size_t)plane * (PIX / 4) + col4;
    const float4 zero = make_float4(0, 0, 0, 0);

    float4 t[10];
#pragma unroll
    for (int j = 0; j < 10; j++) {
        int r = rbase - 3 + j;
        t[j] = (r >= 0 && r < HH) ? bp[(size_t)r * W4] : zero;
    }
#pragma unroll
    for (int k = 0; k < 4; k++) {
        float4 acc = zero;
#pragma unroll
        for (int j = 0; j < 7; j++) {
            float w = g.w[j];
            const float4& v = t[k + j];
            acc.x += w * v.x; acc.y += w * v.y;
            acc.z += w * v.z; acc.w += w * v.w;
        }
        sp[(size_t)(rbase + k) * W4] = acc;
        hist4(myh, acc);
    }

    __syncthreads();
    for (int i = threadIdx.x; i < 4096; i += 256) {
        unsigned v = lh[i] + lh[i + 4096];
        if (v) atomicAdd(&g_hist1[i], v);
    }
}

// ---------------- filtered full-scan histogram passes ----------------
__global__ __launch_bounds__(256) void hist_mid(const float* __restrict__ S) {
    __shared__ unsigned lh[2 * 4096];
    __shared__ unsigned s_b1;
    for (int i = threadIdx.x; i < 2 * 4096; i += 256) lh[i] = 0;
    if (threadIdx.x == 0) s_b1 = atomicAdd(&g_ctrl[0], 0u);   // coherent read
    __syncthreads();
    unsigned* myh = lh + (threadIdx.x & 1) * 4096;
    unsigned b1 = s_b1;
    const float4* S4 = (const float4*)S;
    long long stride = (long long)gridDim.x * 256;
    for (long long i = (long long)blockIdx.x * 256 + threadIdx.x; i < TOT / 4; i += stride) {
        float4 v = S4[i];
        unsigned k0 = f2key(v.x), k1 = f2key(v.y), k2 = f2key(v.z), k3 = f2key(v.w);
        if ((k0 >> 20) == b1) atomicAdd(&myh[(k0 >> 8) & 0xFFFu], 1u);
        if ((k1 >> 20) == b1) atomicAdd(&myh[(k1 >> 8) & 0xFFFu], 1u);
        if ((k2 >> 20) == b1) atomicAdd(&myh[(k2 >> 8) & 0xFFFu], 1u);
        if ((k3 >> 20) == b1) atomicAdd(&myh[(k3 >> 8) & 0xFFFu], 1u);
    }
    __syncthreads();
    for (int i = threadIdx.x; i < 4096; i += 256) {
        unsigned v = lh[i] + lh[i + 4096];
        if (v) atomicAdd(&g_hist2[i], v);
    }
}

__global__ __launch_bounds__(256) void hist_low(const float* __restrict__ S) {
    __shared__ unsigned lh[2 * 256];
    __shared__ unsigned s_p2;
    for (int i = threadIdx.x; i < 2 * 256; i += 256) lh[i] = 0;
    if (threadIdx.x == 0) {
        unsigned c0 = atomicAdd(&g_ctrl[0], 0u);
        unsigned c1 = atomicAdd(&g_ctrl[1], 0u);
        s_p2 = (c0 << 12) | c1;
    }
    __syncthreads();
    unsigned* myh = lh + (threadIdx.x & 1) * 256;
    unsigned p2 = s_p2;
    const float4* S4 = (const float4*)S;
    long long stride = (long long)gridDim.x * 256;
    for (long long i = (long long)blockIdx.x * 256 + threadIdx.x; i < TOT / 4; i += stride) {
        float4 v = S4[i];
        unsigned k0 = f2key(v.x), k1 = f2key(v.y), k2 = f2key(v.z), k3 = f2key(v.w);
        if ((k0 >> 8) == p2) atomicAdd(&myh[k0 & 0xFFu], 1u);
        if ((k1 >> 8) == p2) atomicAdd(&myh[k1 & 0xFFu], 1u);
        if ((k2 >> 8) == p2) atomicAdd(&myh[k2 & 0xFFu], 1u);
        if ((k3 >> 8) == p2) atomicAdd(&myh[k3 & 0xFFu], 1u);
    }
    __syncthreads();
    if (threadIdx.x < 256) {
        unsigned s = lh[threadIdx.x] + lh[threadIdx.x + 256];
        if (s) atomicAdd(&g_hist3[threadIdx.x], s);
    }
}

__global__ __launch_bounds__(256) void select_k(int which) {
    __shared__ unsigned cnt[4096];
    __shared__ unsigned csum[256];
    int t = threadIdx.x;
    int nbins = (which == 2) ? 256 : 4096;
    unsigned* hsrc = (which == 0) ? g_hist1 : (which == 1) ? g_hist2 : g_hist3;
    int per = nbins >> 8;
    for (int i = t; i < nbins; i += 256) cnt[i] = atomicAdd(&hsrc[i], 0u);  // coherent
    __syncthreads();
    unsigned s = 0;
    for (int j = 0; j < per; j++) s += cnt[t * per + j];
    csum[t] = s;
    __syncthreads();
    if (t == 0) {
        unsigned r = (which == 0) ? MED_RANK
                   : (which == 1) ? atomicAdd(&g_ctrl[3], 0u)
                                  : atomicAdd(&g_ctrl[4], 0u);
        unsigned acc = 0; int c = 0;
        for (; c < 256; c++) { if (acc + csum[c] > r) break; acc += csum[c]; }
        int b = c * per;
        for (;; b++) { if (acc + cnt[b] > r) break; acc += cnt[b]; }
        if (which == 0)      { atomicExch(&g_ctrl[0], (unsigned)b); atomicExch(&g_ctrl[3], r - acc); }
        else if (which == 1) { atomicExch(&g_ctrl[1], (unsigned)b); atomicExch(&g_ctrl[4], r - acc); }
        else {
            unsigned b1 = atomicAdd(&g_ctrl[0], 0u);
            unsigned b2 = atomicAdd(&g_ctrl[1], 0u);
            atomicExch(&g_ctrl[2], (unsigned)b);
            unsigned key = (b1 << 20) | (b2 << 8) | (unsigned)b;
            unsigned bits = (key & 0x80000000u) ? (key ^ 0x80000000u) : ~key;
            atomicExch(&g_med, __uint_as_float(bits));
        }
    }
}

// ---------------- Pass H: threshold + separable 7x7 NMS + mask -------------
#define OX 64
#define OY 16
__global__ __launch_bounds__(256) void nms_kernel(const float* __restrict__ S,
                                                  float* __restrict__ out) {
    __shared__ float tin[22][72];
    __shared__ float hm[22][72];
    __shared__ float s_med;
    if (threadIdx.x == 0) s_med = atomicAdd(&g_med, 0.0f);    // coherent read
    __syncthreads();
    float med = s_med;
    int plane = blockIdx.z;
    int bx = blockIdx.x * OX, by = blockIdx.y * OY;
    const float* Sp = S + (size_t)plane * PIX;
    int t = threadIdx.x;

    for (int i = t; i < 22 * 70; i += 256) {
        int r = i / 70, c = i % 70;
        int ghh = by + r - 3, gww = bx + c - 3;
        float v = -INFINITY;                  // OOB never wins (reduce_window -inf)
        if (ghh >= 0 && ghh < HH && gww >= 0 && gww < WW) {
            float s = Sp[(size_t)ghh * WW + gww];
            v = (s > med) ? s : 0.f;
        }
        tin[r][c] = v;
    }
    __syncthreads();
    for (int i = t; i < 22 * 64; i += 256) {
        int r = i / 64, c = i % 64;
        float m = tin[r][c];
#pragma unroll
        for (int d = 1; d < 7; d++) m = fmaxf(m, tin[r][c + d]);
        hm[r][c] = m;
    }
    __syncthreads();
    int c = t & 63, rq = t >> 6;
#pragma unroll
    for (int s = 0; s < 4; s++) {
        int ro = rq * 4 + s;
        float m = hm[ro][c];
#pragma unroll
        for (int d = 1; d < 7; d++) m = fmaxf(m, hm[ro + d][c]);
        float c0 = tin[ro + 3][c + 3];
        float o = (c0 == m) ? c0 : 0.f;
        out[(size_t)plane * PIX + (size_t)(by + ro) * WW + (bx + c)] = o;
    }
}

// ---------------- Launch ----------------
extern "C" void kernel_launch(void* const* d_in, const int* in_sizes, int n_in,
                              void* d_out, int out_size, void* d_ws, size_t ws_size,
                              hipStream_t stream) {
    const float* x = (const float*)d_in[0];
    float* O = (float*)d_out;                 // scratch until final NMS write
    float* W = (float*)d_ws;                  // S buffer (TOT floats)

    GW g;
    {
        double gg[7], s = 0.0;
        for (int i = 0; i < 7; i++) { double r = i - 3.0; gg[i] = exp(-r * r / 50.0); s += gg[i]; }
        for (int i = 0; i < 7; i++) g.w[i] = (float)(gg[i] / s);
    }

    zero_state<<<16, 256, 0, stream>>>();
    // A: x -> Bh (in d_out)
    sobel_gauss_h<<<dim3(WW / 1024, HH, NIMG), 256, 0, stream>>>(x, O, g);
    // B: Bh -> S (in d_ws), hist0 fused; 12*512*512/256 = 12288 blocks
    gauss_v_hist<<<12288, 256, 0, stream>>>(O, W, g);
    select_k<<<1, 256, 0, stream>>>(0);
    hist_mid<<<8192, 256, 0, stream>>>(W);
    select_k<<<1, 256, 0, stream>>>(1);
    hist_low<<<8192, 256, 0, stream>>>(W);
    select_k<<<1, 256, 0, stream>>>(2);
    // H: threshold + NMS + mask: S -> out
    nms_kernel<<<dim3(WW / OX, HH / OY, PLANES), 256, 0, stream>>>(W, O);
}

// Round 7
// 815.607 us; speedup vs baseline: 1.6380x; 1.6380x over previous
//
#include <hip/hip_runtime.h>
#include <math.h>

#define HH 2048
#define WW 2048
#define NIMG 4
#define NCH 3
#define PLANES (NIMG*NCH)            // 12
#define PIX (HH*WW)                  // 4194304
#define TOT (PLANES*PIX)             // 50331648
#define W4 (WW/4)                    // 512
#define MED_RANK 25165823u           // floor(0.5*(TOT-1)), method='lower'

struct GW { float w[7]; };

// ---------------- module-global device state ----------------
// Cross-kernel visibility relies on kernel-boundary acquire/release (HSA memory
// model): plain stores in kernel K are visible to plain loads in kernel K+1.
// Proven by r4's passing run. Do NOT use per-block same-address atomics for
// these — 49k blocks x 1 atomic on one address cost ~500us in r6.
__device__ unsigned g_hist1[4096];
__device__ unsigned g_hist2[4096];
__device__ unsigned g_hist3[256];
__device__ unsigned g_ctrl[8];   // [0]=b1 [1]=b2 [2]=b3 [3]=rank2 [4]=rank3
__device__ float    g_med;

__global__ void zero_state() {
    int t = blockIdx.x * 256 + threadIdx.x;
    if (t < 4096) { g_hist1[t] = 0; g_hist2[t] = 0; }
    if (t < 256)  g_hist3[t] = 0;
    if (t < 8)    g_ctrl[t] = 0;
    if (t == 0)   g_med = 0.f;
}

// ---------------- Pass A: fused Sobel + horizontal Gaussian ----------------
__global__ __launch_bounds__(256) void sobel_gauss_h(const float* __restrict__ x,
                                                     float* __restrict__ Bh, GW g) {
    int w0 = (blockIdx.x * 256 + threadIdx.x) * 4;     // 0..2044
    int h  = blockIdx.y;
    int n  = blockIdx.z;
    const float* xp = x + (size_t)n * PIX;
    const float* p0 = xp + (size_t)(h - 1) * WW;
    const float* p1 = xp + (size_t)h * WW;
    const float* p2 = xp + (size_t)(h + 1) * WW;
    bool has0 = (h > 0), has2 = (h < HH - 1);

    float r0[12], r1[12], r2[12];
    if (w0 >= 4 && w0 <= WW - 8) {          // interior: 9 float4 loads
#pragma unroll
        for (int b = 0; b < 3; b++) {
            int col = w0 - 4 + b * 4;
            float4 v0 = has0 ? *(const float4*)(p0 + col) : make_float4(0, 0, 0, 0);
            float4 v1 = *(const float4*)(p1 + col);
            float4 v2 = has2 ? *(const float4*)(p2 + col) : make_float4(0, 0, 0, 0);
            r0[b*4+0]=v0.x; r0[b*4+1]=v0.y; r0[b*4+2]=v0.z; r0[b*4+3]=v0.w;
            r1[b*4+0]=v1.x; r1[b*4+1]=v1.y; r1[b*4+2]=v1.z; r1[b*4+3]=v1.w;
            r2[b*4+0]=v2.x; r2[b*4+1]=v2.y; r2[b*4+2]=v2.z; r2[b*4+3]=v2.w;
        }
    } else {
#pragma unroll
        for (int i = 0; i < 12; i++) {
            int col = w0 - 4 + i;
            bool okc = (col >= 0 && col < WW);
            r0[i] = (okc && has0) ? p0[col] : 0.f;
            r1[i] =  okc          ? p1[col] : 0.f;
            r2[i] = (okc && has2) ? p2[col] : 0.f;
        }
    }

    float pxx[10], pyy[10], pxy[10];
#pragma unroll
    for (int c = 0; c < 10; c++) {
        int ai = c + 1;
        int cg = w0 - 3 + c;
        float Ix = (r0[ai+1] - r0[ai-1]) + 2.f*(r1[ai+1] - r1[ai-1]) + (r2[ai+1] - r2[ai-1]);
        float Iy = (r2[ai-1] - r0[ai-1]) + 2.f*(r2[ai]   - r0[ai])   + (r2[ai+1] - r0[ai+1]);
        bool ok = (cg >= 0 && cg < WW);
        pxx[c] = ok ? Ix * Ix : 0.f;
        pyy[c] = ok ? Iy * Iy : 0.f;
        pxy[c] = ok ? Ix * Iy : 0.f;
    }

    float oxx[4], oyy[4], oxy[4];
#pragma unroll
    for (int k = 0; k < 4; k++) {
        float sxx = 0.f, syy = 0.f, sxy = 0.f;
#pragma unroll
        for (int j = 0; j < 7; j++) {
            sxx += g.w[j] * pxx[k + j];
            syy += g.w[j] * pyy[k + j];
            sxy += g.w[j] * pxy[k + j];
        }
        oxx[k] = sxx; oyy[k] = syy; oxy[k] = sxy;
    }

    size_t base = (size_t)(n * NCH) * PIX + (size_t)h * WW + w0;
    *(float4*)(Bh + base)           = make_float4(oxx[0], oxx[1], oxx[2], oxx[3]);
    *(float4*)(Bh + base + PIX)     = make_float4(oyy[0], oyy[1], oyy[2], oyy[3]);
    *(float4*)(Bh + base + 2*PIX)   = make_float4(oxy[0], oxy[1], oxy[2], oxy[3]);
}

// ---------------- Median helpers ----------------
__device__ __forceinline__ unsigned f2key(float f) {
    unsigned b = __float_as_uint(f);
    return (b & 0x80000000u) ? ~b : (b | 0x80000000u);
}

__device__ __forceinline__ void hist4(unsigned* myh, const float4& a) {
    unsigned b0 = f2key(a.x) >> 20, b1 = f2key(a.y) >> 20,
             b2 = f2key(a.z) >> 20, b3 = f2key(a.w) >> 20;
    if (b0 == b1 && b0 == b2 && b0 == b3) {      // spatially-correlated fast path
        atomicAdd(&myh[b0], 4u);
    } else {
        atomicAdd(&myh[b0], 1u); atomicAdd(&myh[b1], 1u);
        atomicAdd(&myh[b2], 1u); atomicAdd(&myh[b3], 1u);
    }
}

// ---------------- Pass B: vertical Gaussian + fused hist0 ----------------
// Thread = one float4 column x 4 consecutive output rows: 10 guarded loads ->
// 4 outputs (2.5x read amplification). 12*512*512/256 = 12288 blocks. [r6-proven]
__global__ __launch_bounds__(256) void gauss_v_hist(const float* __restrict__ Bh,
                                                    float* __restrict__ S, GW g) {
    __shared__ unsigned lh[2 * 4096];            // 2 lane-parity copies, 32 KB
    for (int i = threadIdx.x; i < 2 * 4096; i += 256) lh[i] = 0;
    __syncthreads();
    unsigned* myh = lh + (threadIdx.x & 1) * 4096;

    int e = blockIdx.x * 256 + threadIdx.x;      // < 12*512*512 = 3145728
    int col4  = e & (W4 - 1);
    int rg    = (e >> 9) & 511;
    int plane = e >> 18;                         // < 12
    int rbase = rg * 4;
    const float4* bp = (const float4*)Bh + (size_t)plane * (PIX / 4) + col4;
    float4*       sp = (float4*)S        + (size_t)plane * (PIX / 4) + col4;
    const float4 zero = make_float4(0, 0, 0, 0);

    float4 t[10];
#pragma unroll
    for (int j = 0; j < 10; j++) {
        int r = rbase - 3 + j;
        t[j] = (r >= 0 && r < HH) ? bp[(size_t)r * W4] : zero;
    }
#pragma unroll
    for (int k = 0; k < 4; k++) {
        float4 acc = zero;
#pragma unroll
        for (int j = 0; j < 7; j++) {
            float w = g.w[j];
            const float4& v = t[k + j];
            acc.x += w * v.x; acc.y += w * v.y;
            acc.z += w * v.z; acc.w += w * v.w;
        }
        sp[(size_t)(rbase + k) * W4] = acc;
        hist4(myh, acc);
    }

    __syncthreads();
    for (int i = threadIdx.x; i < 4096; i += 256) {
        unsigned v = lh[i] + lh[i + 4096];
        if (v) atomicAdd(&g_hist1[i], v);
    }
}

// ---------------- filtered full-scan histogram passes [r4-proven] ----------
__global__ __launch_bounds__(256) void hist_mid(const float* __restrict__ S) {
    __shared__ unsigned lh[2 * 4096];
    for (int i = threadIdx.x; i < 2 * 4096; i += 256) lh[i] = 0;
    __syncthreads();
    unsigned* myh = lh + (threadIdx.x & 1) * 4096;
    unsigned b1 = g_ctrl[0];
    const float4* S4 = (const float4*)S;
    long long stride = (long long)gridDim.x * 256;
    for (long long i = (long long)blockIdx.x * 256 + threadIdx.x; i < TOT / 4; i += stride) {
        float4 v = S4[i];
        unsigned k0 = f2key(v.x), k1 = f2key(v.y), k2 = f2key(v.z), k3 = f2key(v.w);
        if ((k0 >> 20) == b1) atomicAdd(&myh[(k0 >> 8) & 0xFFFu], 1u);
        if ((k1 >> 20) == b1) atomicAdd(&myh[(k1 >> 8) & 0xFFFu], 1u);
        if ((k2 >> 20) == b1) atomicAdd(&myh[(k2 >> 8) & 0xFFFu], 1u);
        if ((k3 >> 20) == b1) atomicAdd(&myh[(k3 >> 8) & 0xFFFu], 1u);
    }
    __syncthreads();
    for (int i = threadIdx.x; i < 4096; i += 256) {
        unsigned v = lh[i] + lh[i + 4096];
        if (v) atomicAdd(&g_hist2[i], v);
    }
}

__global__ __launch_bounds__(256) void hist_low(const float* __restrict__ S) {
    __shared__ unsigned lh[2 * 256];
    for (int i = threadIdx.x; i < 2 * 256; i += 256) lh[i] = 0;
    __syncthreads();
    unsigned* myh = lh + (threadIdx.x & 1) * 256;
    unsigned p2 = (g_ctrl[0] << 12) | g_ctrl[1];
    const float4* S4 = (const float4*)S;
    long long stride = (long long)gridDim.x * 256;
    for (long long i = (long long)blockIdx.x * 256 + threadIdx.x; i < TOT / 4; i += stride) {
        float4 v = S4[i];
        unsigned k0 = f2key(v.x), k1 = f2key(v.y), k2 = f2key(v.z), k3 = f2key(v.w);
        if ((k0 >> 8) == p2) atomicAdd(&myh[k0 & 0xFFu], 1u);
        if ((k1 >> 8) == p2) atomicAdd(&myh[k1 & 0xFFu], 1u);
        if ((k2 >> 8) == p2) atomicAdd(&myh[k2 & 0xFFu], 1u);
        if ((k3 >> 8) == p2) atomicAdd(&myh[k3 & 0xFFu], 1u);
    }
    __syncthreads();
    if (threadIdx.x < 256) {
        unsigned s = lh[threadIdx.x] + lh[threadIdx.x + 256];
        if (s) atomicAdd(&g_hist3[threadIdx.x], s);
    }
}

__global__ __launch_bounds__(256) void select_k(int which) {
    __shared__ unsigned cnt[4096];
    __shared__ unsigned csum[256];
    int t = threadIdx.x;
    int nbins = (which == 2) ? 256 : 4096;
    const unsigned* hsrc = (which == 0) ? g_hist1 : (which == 1) ? g_hist2 : g_hist3;
    unsigned r = (which == 0) ? MED_RANK : (which == 1) ? g_ctrl[3] : g_ctrl[4];
    int per = nbins >> 8;
    for (int i = t; i < nbins; i += 256) cnt[i] = hsrc[i];
    __syncthreads();
    unsigned s = 0;
    for (int j = 0; j < per; j++) s += cnt[t * per + j];
    csum[t] = s;
    __syncthreads();
    if (t == 0) {
        unsigned acc = 0; int c = 0;
        for (; c < 256; c++) { if (acc + csum[c] > r) break; acc += csum[c]; }
        int b = c * per;
        for (;; b++) { if (acc + cnt[b] > r) break; acc += cnt[b]; }
        if (which == 0)      { g_ctrl[0] = (unsigned)b; g_ctrl[3] = r - acc; }
        else if (which == 1) { g_ctrl[1] = (unsigned)b; g_ctrl[4] = r - acc; }
        else {
            g_ctrl[2] = (unsigned)b;
            unsigned key = (g_ctrl[0] << 20) | (g_ctrl[1] << 8) | (unsigned)b;
            unsigned bits = (key & 0x80000000u) ? (key ^ 0x80000000u) : ~key;
            g_med = __uint_as_float(bits);
        }
    }
}

// ---------------- Pass H: threshold + separable 7x7 NMS + mask [r4-proven] -
#define OX 64
#define OY 16
__global__ __launch_bounds__(256) void nms_kernel(const float* __restrict__ S,
                                                  float* __restrict__ out) {
    __shared__ float tin[22][72];
    __shared__ float hm[22][72];
    float med = g_med;                        // uniform scalar load, K$-cached
    int plane = blockIdx.z;
    int bx = blockIdx.x * OX, by = blockIdx.y * OY;
    const float* Sp = S + (size_t)plane * PIX;
    int t = threadIdx.x;

    for (int i = t; i < 22 * 70; i += 256) {
        int r = i / 70, c = i % 70;
        int ghh = by + r - 3, gww = bx + c - 3;
        float v = -INFINITY;                  // OOB never wins (reduce_window -inf)
        if (ghh >= 0 && ghh < HH && gww >= 0 && gww < WW) {
            float s = Sp[(size_t)ghh * WW + gww];
            v = (s > med) ? s : 0.f;
        }
        tin[r][c] = v;
    }
    __syncthreads();
    for (int i = t; i < 22 * 64; i += 256) {
        int r = i / 64, c = i % 64;
        float m = tin[r][c];
#pragma unroll
        for (int d = 1; d < 7; d++) m = fmaxf(m, tin[r][c + d]);
        hm[r][c] = m;
    }
    __syncthreads();
    int c = t & 63, rq = t >> 6;
#pragma unroll
    for (int s = 0; s < 4; s++) {
        int ro = rq * 4 + s;
        float m = hm[ro][c];
#pragma unroll
        for (int d = 1; d < 7; d++) m = fmaxf(m, hm[ro + d][c]);
        float c0 = tin[ro + 3][c + 3];
        float o = (c0 == m) ? c0 : 0.f;
        out[(size_t)plane * PIX + (size_t)(by + ro) * WW + (bx + c)] = o;
    }
}

// ---------------- Launch ----------------
extern "C" void kernel_launch(void* const* d_in, const int* in_sizes, int n_in,
                              void* d_out, int out_size, void* d_ws, size_t ws_size,
                              hipStream_t stream) {
    const float* x = (const float*)d_in[0];
    float* O = (float*)d_out;                 // scratch until final NMS write
    float* W = (float*)d_ws;                  // S buffer (TOT floats)

    GW g;
    {
        double gg[7], s = 0.0;
        for (int i = 0; i < 7; i++) { double r = i - 3.0; gg[i] = exp(-r * r / 50.0); s += gg[i]; }
        for (int i = 0; i < 7; i++) g.w[i] = (float)(gg[i] / s);
    }

    zero_state<<<16, 256, 0, stream>>>();
    // A: x -> Bh (in d_out)
    sobel_gauss_h<<<dim3(WW / 1024, HH, NIMG), 256, 0, stream>>>(x, O, g);
    // B: Bh -> S (in d_ws), hist0 fused; 12*512*512/256 = 12288 blocks
    gauss_v_hist<<<12288, 256, 0, stream>>>(O, W, g);
    select_k<<<1, 256, 0, stream>>>(0);
    hist_mid<<<8192, 256, 0, stream>>>(W);
    select_k<<<1, 256, 0, stream>>>(1);
    hist_low<<<8192, 256, 0, stream>>>(W);
    select_k<<<1, 256, 0, stream>>>(2);
    // H: threshold + NMS + mask: S -> out
    nms_kernel<<<dim3(WW / OX, HH / OY, PLANES), 256, 0, stream>>>(W, O);
}